// Round 6
// baseline (283.949 us; speedup 1.0000x reference)
//
#include <hip/hip_runtime.h>

typedef __bf16 bf16;
typedef __bf16 bf16x8 __attribute__((ext_vector_type(8)));
typedef unsigned short u16x8 __attribute__((ext_vector_type(8)));
typedef float f32x4 __attribute__((ext_vector_type(4)));

#define HH 128
#define WW 128
#define HP 130

// ---------------------------------------------------------------------------
// Transpose all three inputs; also writes the zero rings (no memset needed).
// z<4: fs->fs_t(bf16), z<8: ctx->ctx_t(bf16), z<12: x->xp(f32)
// ---------------------------------------------------------------------------
__global__ __launch_bounds__(256) void transpose_all(
    const float* __restrict__ fs, const float* __restrict__ ctx,
    const float* __restrict__ x, bf16* __restrict__ fs_t,
    bf16* __restrict__ ctx_t, float* __restrict__ xp) {
  __shared__ float tile[64][65];
  const int z = blockIdx.z;
  const int b = z & 3, which = z >> 2;
  const float* in = which == 0 ? fs : (which == 1 ? ctx : x);
  const int y = blockIdx.y, x0 = blockIdx.x * 64;
  const int tid = threadIdx.x;
#pragma unroll
  for (int pass = 0; pass < 16; ++pass) {
    int ci = pass * 4 + (tid >> 6), xx = tid & 63;
    tile[ci][xx] = in[((b * 64 + ci) * HH + y) * WW + x0 + xx];
  }
  __syncthreads();
  if (which == 2) {
#pragma unroll
    for (int pass = 0; pass < 16; ++pass) {
      int xx = pass * 4 + (tid >> 6), ci = tid & 63;
      xp[((size_t)(b * HP + y + 1) * HP + (x0 + xx + 1)) * 64 + ci] = tile[ci][xx];
    }
    if (x0 == 0 && tid < 64) xp[((size_t)(b * HP + y + 1) * HP + 0) * 64 + tid] = 0.f;
    if (x0 == 64 && tid < 64) xp[((size_t)(b * HP + y + 1) * HP + 129) * 64 + tid] = 0.f;
    if (y == 0)
      for (int i = tid; i < 4160; i += 256) {
        int xx = (x0 == 0 ? 0 : 65) + (i >> 6);
        xp[((size_t)(b * HP + 0) * HP + xx) * 64 + (i & 63)] = 0.f;
      }
    if (y == 127)
      for (int i = tid; i < 4160; i += 256) {
        int xx = (x0 == 0 ? 0 : 65) + (i >> 6);
        xp[((size_t)(b * HP + 129) * HP + xx) * 64 + (i & 63)] = 0.f;
      }
  } else {
    bf16* out = which ? ctx_t : fs_t;
#pragma unroll
    for (int pass = 0; pass < 16; ++pass) {
      int xx = pass * 4 + (tid >> 6), ci = tid & 63;
      out[((size_t)(b * HP + y + 1) * HP + (x0 + xx + 1)) * 64 + ci] = (bf16)tile[ci][xx];
    }
    if (x0 == 0 && tid < 64) out[((size_t)(b * HP + y + 1) * HP + 0) * 64 + tid] = (bf16)0.f;
    if (x0 == 64 && tid < 64) out[((size_t)(b * HP + y + 1) * HP + 129) * 64 + tid] = (bf16)0.f;
    if (y == 0)
      for (int i = tid; i < 4160; i += 256) {
        int xx = (x0 == 0 ? 0 : 65) + (i >> 6);
        out[((size_t)(b * HP + 0) * HP + xx) * 64 + (i & 63)] = (bf16)0.f;
      }
    if (y == 127)
      for (int i = tid; i < 4160; i += 256) {
        int xx = (x0 == 0 ? 0 : 65) + (i >> 6);
        out[((size_t)(b * HP + 129) * HP + xx) * 64 + (i & 63)] = (bf16)0.f;
      }
  }
}

// ---------------------------------------------------------------------------
// Build both B-fragment buffers in one kernel.
// PSF: [cc][kc18][nt9][lane][8], column-permuted (n' = t9*64 + c).
// OFFM: [kc18][nt2][lane][8].
// ---------------------------------------------------------------------------
__global__ void build_weights(const float* __restrict__ fw,
                              const float* __restrict__ pw,
                              const float* __restrict__ mw,
                              bf16* __restrict__ Bf, bf16* __restrict__ Bf2) {
  int idx = blockIdx.x * 256 + threadIdx.x;
  if (idx < 41472) {
    int lane = idx & 63;
    int nt = (idx >> 6) % 9;
    int kc = ((idx >> 6) / 9) % 18;
    int cc = (idx >> 6) / 162;
    int np = cc * 144 + nt * 16 + (lane & 15);
    int n = (np & 63) * 9 + (np >> 6);
    int q = lane >> 4;
    bf16x8 v;
#pragma unroll
    for (int j = 0; j < 8; ++j) {
      int k = kc * 32 + q * 8 + j;
      int tap = k >> 6, ci = k & 63;
      v[j] = (bf16)fw[(n * 64 + ci) * 9 + tap];
    }
    *reinterpret_cast<bf16x8*>(Bf + (size_t)idx * 8) = v;
  } else {
    int id2 = idx - 41472;               // [0, 2304)
    if (id2 >= 2304) return;
    int lane = id2 & 63;
    int nt = (id2 >> 6) & 1;
    int kc = (id2 >> 6) >> 1;
    int n = nt * 16 + (lane & 15);
    int q = lane >> 4;
    bf16x8 v;
#pragma unroll
    for (int j = 0; j < 8; ++j) {
      int k = kc * 32 + q * 8 + j;
      int tap = k >> 6, ci = k & 63;
      float w = 0.f;
      if (n < 18) w = pw[(n * 64 + ci) * 9 + tap];
      else if (n < 27) w = mw[((n - 18) * 64 + ci) * 9 + tap];
      v[j] = (bf16)w;
    }
    *reinterpret_cast<bf16x8*>(Bf2 + (size_t)id2 * 8) = v;
  }
}

// ---------------------------------------------------------------------------
// Mega kernel, single launch: blocks [0,256) offset/mask conv (all b),
// blocks [256,1280) PSF GEMM (all b, cc split). B fragments are read
// DIRECTLY global->VGPR (L2-resident, per-lane private 16B loads) — no LDS
// staging, no K-loop barriers, no cross-wave hand-off.
// ---------------------------------------------------------------------------
__global__ __launch_bounds__(256, 2) void conv_mega(
    const bf16* __restrict__ ctx_t, const bf16* __restrict__ fs_t,
    const bf16* __restrict__ Bf, const bf16* __restrict__ Bf2,
    const float* __restrict__ fb, const float* __restrict__ pb,
    const float* __restrict__ mb, bf16* __restrict__ Pg,
    float* __restrict__ OM) {
  __shared__ __align__(16) ushort apatch[324 * 64];   // 41472 B
  const int tid = threadIdx.x;
  const int lane = tid & 63, wv = tid >> 6;
  const int q = lane >> 4, col = lane & 15;
  const int bid = blockIdx.x;

  if (bid < 256) {
    // ---------------- offset/mask conv ----------------
    const int b = bid >> 6, t = bid & 63;
    const int h0 = (t >> 3) * 16, w0 = (t & 7) * 16;
    const ushort* Atu = (const ushort*)fs_t;
#pragma unroll
    for (int it = 0; it < 11; ++it) {
      int flat = it * 256 + tid;
      if (flat < 2592) {
        int px = flat >> 3, c8 = flat & 7;
        int py = px / 18, pxx = px - py * 18;
        u16x8 v = *(const u16x8*)(Atu + ((size_t)((b * HP + h0 + py) * HP + (w0 + pxx))) * 64 + c8 * 8);
        *(u16x8*)(apatch + px * 64 + ((c8 ^ (px & 7)) * 8)) = v;
      }
    }
    __syncthreads();
    f32x4 acc[4][2];
#pragma unroll
    for (int s = 0; s < 4; ++s) {
      acc[s][0] = (f32x4){0.f, 0.f, 0.f, 0.f};
      acc[s][1] = (f32x4){0.f, 0.f, 0.f, 0.f};
    }
    const bf16* bl = Bf2 + lane * 8;
#pragma unroll
    for (int dh = 0; dh < 3; ++dh)
#pragma unroll
      for (int dw = 0; dw < 3; ++dw) {
        const int tap = dh * 3 + dw;
        bf16x8 a[4][2];
#pragma unroll
        for (int s = 0; s < 4; ++s) {
          int p = (s * 4 + wv + dh) * 18 + (col + dw);
#pragma unroll
          for (int hf = 0; hf < 2; ++hf) {
            int ch = (hf * 4 + q) ^ (p & 7);
            a[s][hf] = *(const bf16x8*)((const bf16*)apatch + p * 64 + ch * 8);
          }
        }
#pragma unroll
        for (int hf = 0; hf < 2; ++hf)
#pragma unroll
          for (int nt = 0; nt < 2; ++nt) {
            bf16x8 bb = *(const bf16x8*)(bl + (size_t)(((tap * 2 + hf) * 2 + nt) * 512));
#pragma unroll
            for (int s = 0; s < 4; ++s)
              acc[s][nt] = __builtin_amdgcn_mfma_f32_16x16x32_bf16(a[s][hf], bb, acc[s][nt], 0, 0, 0);
          }
      }
    float* OMb = OM + (size_t)b * 16384 * 32;
#pragma unroll
    for (int nt = 0; nt < 2; ++nt) {
      int n = nt * 16 + col;
#pragma unroll
      for (int s = 0; s < 4; ++s) {
        int h = h0 + s * 4 + wv;
#pragma unroll
        for (int j = 0; j < 4; ++j) {
          int w = w0 + q * 4 + j;
          float v = acc[s][nt][j];
          float r;
          if (n < 18) r = v + pb[n];
          else if (n < 27) { float zz = v + mb[n - 18]; r = 1.f / (1.f + __expf(-zz)); }
          else r = 0.f;
          OMb[(size_t)(h * WW + w) * 32 + n] = r;
        }
      }
    }
    return;
  }

  // ---------------- PSF GEMM (global->VGPR B reads) ----------------
  const int pid = bid - 256;
  const int cc = pid & 3;
  const int rest = pid >> 2;
  const int b = rest >> 6;
  const int t = rest & 63;
  const int h0 = (t >> 3) * 16, w0 = (t & 7) * 16;

  const ushort* Atu = (const ushort*)ctx_t;
#pragma unroll
  for (int it = 0; it < 11; ++it) {
    int flat = it * 256 + tid;
    if (flat < 2592) {
      int px = flat >> 3, c8 = flat & 7;
      int py = px / 18, pxx = px - py * 18;
      u16x8 v = *(const u16x8*)(Atu + ((size_t)((b * HP + h0 + py) * HP + (w0 + pxx))) * 64 + c8 * 8);
      *(u16x8*)(apatch + px * 64 + ((c8 ^ (px & 7)) * 8)) = v;
    }
  }
  __syncthreads();

  f32x4 acc[4][9];
#pragma unroll
  for (int s = 0; s < 4; ++s)
#pragma unroll
    for (int n = 0; n < 9; ++n) acc[s][n] = (f32x4){0.f, 0.f, 0.f, 0.f};

  // B base for this cc: 18 half-stages x 9 nt x 64 lanes x 8 bf16
  const bf16* bl = Bf + (size_t)cc * 82944 + lane * 8;

#pragma unroll
  for (int s = 0; s < 18; ++s) {
    const int tap = s >> 1, hf = s & 1;
    const int dh = tap >= 6 ? 2 : (tap >= 3 ? 1 : 0);
    const int dw = tap - dh * 3;
    bf16x8 a[4];
#pragma unroll
    for (int s4 = 0; s4 < 4; ++s4) {
      int p = (s4 * 4 + wv + dh) * 18 + (col + dw);
      int ch = (hf * 4 + q) ^ (p & 7);
      a[s4] = *(const bf16x8*)((const bf16*)apatch + p * 64 + ch * 8);
    }
    const bf16* bp = bl + (size_t)s * 4608;
#pragma unroll
    for (int nt = 0; nt < 9; ++nt) {
      bf16x8 bb = *(const bf16x8*)(bp + nt * 512);
#pragma unroll
      for (int s4 = 0; s4 < 4; ++s4)
        acc[s4][nt] = __builtin_amdgcn_mfma_f32_16x16x32_bf16(a[s4], bb, acc[s4][nt], 0, 0, 0);
    }
  }

  // epilogue: P[px][n'] (n' = t9*64 + c)
  bf16* Pp = Pg + (size_t)b * 16384 * 576;
#pragma unroll
  for (int nt = 0; nt < 9; ++nt) {
    int np = cc * 144 + nt * 16 + col;
    float bias = fb[(np & 63) * 9 + (np >> 6)];
#pragma unroll
    for (int s = 0; s < 4; ++s) {
      int h = h0 + s * 4 + wv;
#pragma unroll
      for (int j = 0; j < 4; ++j) {
        int w = w0 + q * 4 + j;
        Pp[(size_t)(h * WW + w) * 576 + np] = (bf16)(acc[s][nt][j] + bias);
      }
    }
  }
}

// ---------------------------------------------------------------------------
// Sampler. Block = 8x8 px tile. Phase A: 576 (px,tap) tasks compute bilinear
// weights (x mask) + gather addresses once, into LDS. Phase B: wave = pixel,
// lane = channel; broadcast LDS reads + coalesced 256B gathers + 128B P reads.
// ---------------------------------------------------------------------------
__global__ __launch_bounds__(256, 4) void sampler(
    const bf16* __restrict__ Pg, const float* __restrict__ xp,
    const float* __restrict__ OM, float* __restrict__ out) {
  __shared__ int4 Aaddr[576];
  __shared__ float4 Aw[576];
  __shared__ float outT[64][65];
  const int tid = threadIdx.x;
  const int wv = tid >> 6, c = tid & 63;
  const int blk = blockIdx.x;           // 0..1023
  const int b = blk >> 8;
  const int t = blk & 255;
  const int h0 = (t >> 4) * 8, w0 = (t & 15) * 8;

  const float* OMb = OM + (size_t)b * 16384 * 32;
  for (int task = tid; task < 576; task += 256) {
    int pl = task & 63, t9 = task >> 6;
    int h = h0 + (pl >> 3), w = w0 + (pl & 7);
    int i3 = t9 / 3, j3 = t9 - i3 * 3;
    int dh = (i3 == 0) ? -1 : 0, ri = (i3 == 0) ? 2 : (i3 - 1);
    int dw = (j3 == 0) ? -1 : 0, rj = (j3 == 0) ? 2 : (j3 - 1);
    int hh = h + dh, ww2 = w + dw;
    int4 ad = {0, 0, 0, 0};
    float4 wt = {0.f, 0.f, 0.f, 0.f};
    if (hh >= 0 && ww2 >= 0) {
      const float* omp = OMb + (size_t)(hh * WW + ww2) * 32;
      int np = ri * 3 + rj;
      float ox = omp[np], oy = omp[9 + np], mv = omp[18 + np];
      float px = (float)(hh + ri) + ox;
      float py = (float)(ww2 + rj) + oy;
      float fx = floorf(px), fy = floorf(py);
      float ltx = fminf(fmaxf(fx, 0.f), 129.f);
      float lty = fminf(fmaxf(fy, 0.f), 129.f);
      float rbx = fminf(fmaxf(fx + 1.f, 0.f), 129.f);
      float rby = fminf(fmaxf(fy + 1.f, 0.f), 129.f);
      float pxc = fminf(fmaxf(px, 0.f), 129.f);
      float pyc = fminf(fmaxf(py, 0.f), 129.f);
      float glt = (1.f + ltx - pxc) * (1.f + lty - pyc);
      float grb = (1.f - rbx + pxc) * (1.f - rby + pyc);
      float glb = (1.f + ltx - pxc) * (1.f - rby + pyc);
      float grt = (1.f - rbx + pxc) * (1.f + lty - pyc);
      int ix0 = (int)ltx, iy0 = (int)lty, ix1 = (int)rbx, iy1 = (int)rby;
      ad.x = (ix0 * HP + iy0) * 64;
      ad.y = (ix1 * HP + iy1) * 64;
      ad.z = (ix0 * HP + iy1) * 64;
      ad.w = (ix1 * HP + iy0) * 64;
      wt.x = glt * mv; wt.y = grb * mv; wt.z = glb * mv; wt.w = grt * mv;
    }
    Aaddr[task] = ad;
    Aw[task] = wt;
  }
  __syncthreads();

  const float* xpb = xp + (size_t)b * (HP * HP * 64) + c;
  const bf16* Pb = Pg + (size_t)b * 16384 * 576 + c;
#pragma unroll 4
  for (int k = 0; k < 16; ++k) {
    int pl = wv * 16 + k;
    int h = h0 + (pl >> 3), w = w0 + (pl & 7);
    const bf16* Pp = Pb + (size_t)(h * WW + w) * 576;
    float res = 0.f;
#pragma unroll
    for (int t9 = 0; t9 < 9; ++t9) {
      int4 ad = Aaddr[t9 * 64 + pl];
      float4 wt = Aw[t9 * 64 + pl];
      float xlt = xpb[ad.x];
      float xrb = xpb[ad.y];
      float xlb = xpb[ad.z];
      float xrt = xpb[ad.w];
      float sv = wt.x * xlt + wt.y * xrb + wt.z * xlb + wt.w * xrt;
      res += (float)Pp[t9 * 64] * sv;
    }
    outT[c][pl] = res;
  }
  __syncthreads();

#pragma unroll
  for (int it = 0; it < 4; ++it) {
    int task = it * 256 + tid;                 // 1024 tasks of 16B
    int c2 = task >> 4;
    int rem = task & 15;
    int hrow = rem >> 1, half = rem & 1;
    f32x4 v;
#pragma unroll
    for (int i = 0; i < 4; ++i) v[i] = outT[c2][hrow * 8 + half * 4 + i];
    *reinterpret_cast<f32x4*>(
        out + ((size_t)(b * 64 + c2) * HH + h0 + hrow) * WW + w0 + half * 4) = v;
  }
}

// ---------------------------------------------------------------------------
extern "C" void kernel_launch(void* const* d_in, const int* in_sizes, int n_in,
                              void* d_out, int out_size, void* d_ws, size_t ws_size,
                              hipStream_t stream) {
  (void)in_sizes; (void)n_in; (void)out_size; (void)ws_size;
  const float* fs  = (const float*)d_in[0];
  const float* ctx = (const float*)d_in[1];
  const float* x   = (const float*)d_in[2];
  const float* pw  = (const float*)d_in[3];
  const float* pb  = (const float*)d_in[4];
  const float* fw  = (const float*)d_in[5];
  const float* fb  = (const float*)d_in[6];
  const float* mw  = (const float*)d_in[7];
  const float* mb  = (const float*)d_in[8];

  char* ws = (char*)d_ws;
  bf16*  ctx_t = (bf16*)(ws);                   //  8,652,800
  bf16*  fs_t  = (bf16*)(ws + 8652800);         //  8,652,800
  float* xp    = (float*)(ws + 17305600);       // 17,305,600
  bf16*  Bf    = (bf16*)(ws + 34611200);        //    663,552
  bf16*  Bf2   = (bf16*)(ws + 35274752);        //     36,864
  float* OM    = (float*)(ws + 35311616);       //  8,388,608
  bf16*  Pg    = (bf16*)(ws + 43700224);        // 75,497,472 (4 batches)
                                                // total 119,197,696

  transpose_all<<<dim3(2, 128, 12), 256, 0, stream>>>(fs, ctx, x, fs_t, ctx_t, xp);
  build_weights<<<171, 256, 0, stream>>>(fw, pw, mw, Bf, Bf2);
  conv_mega<<<1280, 256, 0, stream>>>(ctx_t, fs_t, Bf, Bf2, fb, pb, mb, Pg, OM);
  sampler<<<1024, 256, 0, stream>>>(Pg, xp, OM, (float*)d_out);
}